// Round 9
// baseline (217.249 us; speedup 1.0000x reference)
//
#include <hip/hip_runtime.h>
#include <hip/hip_bf16.h>

// LinearAttention collapsed:
//   dots[m,h] = sum_{d in head h} (X@Wk^T)*(X@Wv^T)   [dual GEMM, A in registers f32->bf16]
//   qsum = X @ Wqs^T ; dotb = X @ CB^T                 [piggybacked on bx==0 blocks]
//   cum = cumsum_s((dots + dotb + dbc)*mask^2); coef = cum*(qsum+bqs)
//   out = coef @ WosT + bo ; state[b,h,:,:] = cum[b, S-1, h]

typedef __attribute__((ext_vector_type(4))) float f32x4;
typedef __attribute__((ext_vector_type(8))) short bf16x8;
typedef __attribute__((ext_vector_type(8))) unsigned short u16x8;
typedef unsigned int u32;

#define GLDS16(g, l)                                                            \
  __builtin_amdgcn_global_load_lds((const __attribute__((address_space(1))) u32*)(g), \
                                   (__attribute__((address_space(3))) u32*)(l), 16, 0, 0)
#define MFMA16(a, b, c) __builtin_amdgcn_mfma_f32_16x16x32_bf16(a, b, c, 0, 0, 0)
#define LGK0 do { asm volatile("s_waitcnt lgkmcnt(0)" ::: "memory"); \
                  __builtin_amdgcn_sched_barrier(0); } while (0)

__device__ __forceinline__ unsigned short f2bf(float f) {
  union { float f; u32 u; } x; x.f = f;
  u32 r = (x.u + 0x7fffu + ((x.u >> 16) & 1u)) >> 16;
  return (unsigned short)r;
}

__device__ __forceinline__ bf16x8 pack8(const f32x4& lo, const f32x4& hi) {
  union { bf16x8 v; u32 w[4]; } r;
  union { __hip_bfloat162 h; u32 u; } c;
  c.h = __float22bfloat162_rn(make_float2(lo.x, lo.y)); r.w[0] = c.u;
  c.h = __float22bfloat162_rn(make_float2(lo.z, lo.w)); r.w[1] = c.u;
  c.h = __float22bfloat162_rn(make_float2(hi.x, hi.y)); r.w[2] = c.u;
  c.h = __float22bfloat162_rn(make_float2(hi.z, hi.w)); r.w[3] = c.u;
  return r.v;
}

// ---------------- prep: Wk/Wv->bf16 + weight sums (no X convert) ----------------
__global__ void k_prep(const float* __restrict__ Wq, const float* __restrict__ bq,
                       const float* __restrict__ Wk, const float* __restrict__ bk,
                       const float* __restrict__ Wv, const float* __restrict__ bv,
                       const float* __restrict__ Wo,
                       unsigned short* __restrict__ Wkb, unsigned short* __restrict__ Wvb,
                       unsigned short* __restrict__ SWb, float* __restrict__ WosT,
                       float* __restrict__ scal) {
  int blk = blockIdx.x, t = threadIdx.x;
  if (blk < 2048) {
    const float* src = (blk < 1024) ? Wk : Wv;
    unsigned short* dst = (blk < 1024) ? Wkb : Wvb;
    size_t i = ((size_t)(blk & 1023) * 256 + t) * 4;
    f32x4 v = *(const f32x4*)(src + i);
    dst[i + 0] = f2bf(v.x); dst[i + 1] = f2bf(v.y);
    dst[i + 2] = f2bf(v.z); dst[i + 3] = f2bf(v.w);
  } else {
    int b2 = blk - 2048;
    if (b2 < 128) {
      int o = b2 * 256 + t;
      int r = o >> 10, c = o & 1023;
      float s = 0.f;
      if (r < 16) {
        for (int d = 0; d < 64; ++d) s += Wq[(size_t)(r * 64 + d) * 1024 + c];
      } else {
        int h = r - 16;
        for (int d = 0; d < 64; ++d) {
          int j = h * 64 + d;
          s += bv[j] * Wk[(size_t)j * 1024 + c] + bk[j] * Wv[(size_t)j * 1024 + c];
        }
      }
      SWb[o] = f2bf(s);
    } else if (b2 < 192) {
      int o = (b2 - 128) * 256 + t;
      int h = o >> 10, j = o & 1023;
      float s = 0.f;
      for (int d = 0; d < 64; ++d) s += Wo[(size_t)j * 1024 + h * 64 + d];
      WosT[o] = s;
    } else {
      if (t < 16) {
        float s = 0.f;
        for (int d = 0; d < 64; ++d) s += bq[t * 64 + d];
        scal[t] = s;
      } else if (t < 32) {
        int h = t - 16;
        float s = 0.f;
        for (int d = 0; d < 64; ++d) s += bk[h * 64 + d] * bv[h * 64 + d];
        scal[t] = s;
      }
    }
  }
}

// ---------------- dual GEMM: BM=256, BN=128, BK=32, 8 waves (4M x 2N) ----------------
// A lives in REGISTERS: 8x global_load_dwordx4 f32 for tile t+1 issued in half-1 of t;
// pack8 -> bf16 frags at half-1 of t+1 (overlaps bk ds_read). B (Wk/Wv/SW) in LDS via
// global_load_lds depth-3, 4 buffers, R2-proven swizzle. One vmcnt+barrier per tile.
// Per-wave vmem queue at boundary of t: [B(t+2) 2][A(t+1) 8][B(t+3) 2] -> vmcnt(2) (swv 3).
// Buffer (elems): Bk@0 (4096), Bv@4096 (4096), SW@8192 (1024) = 9216; 4 bufs = 73728 B.
#define NT 32
#define BUFS 9216
__global__ __launch_bounds__(512, 2) void k_dualgemm(
    const float* __restrict__ X,
    const unsigned short* __restrict__ Wkb,
    const unsigned short* __restrict__ Wvb,
    const unsigned short* __restrict__ SWb,
    float* __restrict__ dotsT, float* __restrict__ qsumT, float* __restrict__ dotbT) {
  extern __shared__ __align__(16) unsigned short lds[];
  int orig = blockIdx.x;
  int wg = (orig & 7) * 64 + (orig >> 3);    // XCD-chunked swizzle (512 % 8 == 0)
  int bx = wg & 7, by = wg >> 3;
  int row0 = by << 8, col0 = bx << 7;
  int tid = threadIdx.x, wid = tid >> 6, lane = tid & 63;
  int wrM = wid >> 1, wcN = wid & 1;
  int fr = lane & 15, fg = lane >> 4;
  bool side = (bx == 0);
  bool swv = side && (wid < 2);

  // ---- A register-staging sources: lane (fr,fg) owns rows wrM*64+mi*16+fr, cols fg*8.. ----
  const float* pA[4];
#pragma unroll
  for (int mi = 0; mi < 4; ++mi)
    pA[mi] = X + (size_t)(row0 + wrM * 64 + mi * 16 + fr) * 1024 + fg * 8;

  // ---- B/SW staging sources (pre-swizzled 16B units, R2-proven) ----
  int rB = tid >> 2;
  int uswB = (((tid & 3) ^ ((tid >> 3) & 3)) << 3);
  const unsigned short* sK = Wkb + (size_t)(col0 + rB) * 1024 + uswB;
  const unsigned short* sV = Wvb + (size_t)(col0 + rB) * 1024 + uswB;
  const unsigned short* sS = SWb + (size_t)rB * 1024 + uswB;           // waves 0,1 only
  int dK = wid << 9, dV = 4096 + (wid << 9), dS = 8192 + (wid << 9);

  // ---- B fragment read offsets (R2-proven, 0-conflict) ----
  int ubo = (fg ^ ((fr >> 1) & 3)) << 3;
  int bro = (wcN * 64 + fr) * 32 + ubo;            // + ni*512
  int swo = 8192 + (wcN * 16 + fr) * 32 + ubo;

  f32x4 ck[4][4] = {{0}}, cv[4][4] = {{0}};
  f32x4 qa[4] = {0, 0, 0, 0};
  f32x4 stgL[4], stgH[4];

  // ---- prologue: A(0)->regs; B(0,1,2) via glds ----
#pragma unroll
  for (int mi = 0; mi < 4; ++mi) {
    stgL[mi] = *(const f32x4*)(pA[mi]);
    stgH[mi] = *(const f32x4*)(pA[mi] + 4);
  }
#pragma unroll
  for (int p = 0; p < 3; ++p) {
    int ko = p << 5;
    GLDS16(sK + ko, lds + p * BUFS + dK);
    GLDS16(sV + ko, lds + p * BUFS + dV);
    if (swv) GLDS16(sS + ko, lds + p * BUFS + dS);
  }
  if (swv) { asm volatile("s_waitcnt vmcnt(6)" ::: "memory"); }
  else     { asm volatile("s_waitcnt vmcnt(4)" ::: "memory"); }
  __builtin_amdgcn_s_barrier();

  for (int t = 0; t < NT; ++t) {
    const int rb = (t & 3) * BUFS;
    const bool st1 = (t + 1 < NT);
    const bool st3 = (t + 3 < NT);
    const int ko1 = (t + 1) << 5;
    const int ko3 = (t + 3) << 5;
    const int wb3 = ((t + 3) & 3) * BUFS;

    // ---- half 1: pack A(t), issue A(t+1)+B(t+3), read bk, 16 MFMA ck
    bf16x8 a[4], bk[4];
#pragma unroll
    for (int mi = 0; mi < 4; ++mi) a[mi] = pack8(stgL[mi], stgH[mi]);
    if (st1) {
#pragma unroll
      for (int mi = 0; mi < 4; ++mi) {
        stgL[mi] = *(const f32x4*)(pA[mi] + ko1);
        stgH[mi] = *(const f32x4*)(pA[mi] + ko1 + 4);
      }
    }
    if (st3) {
      GLDS16(sK + ko3, lds + wb3 + dK);
      GLDS16(sV + ko3, lds + wb3 + dV);
      if (swv) GLDS16(sS + ko3, lds + wb3 + dS);
    }
#pragma unroll
    for (int ni = 0; ni < 4; ++ni) bk[ni] = *(const bf16x8*)(lds + rb + bro + ni * 512);
    LGK0;
    __builtin_amdgcn_s_setprio(1);
#pragma unroll
    for (int mi = 0; mi < 4; ++mi)
#pragma unroll
      for (int ni = 0; ni < 4; ++ni)
        ck[mi][ni] = MFMA16(a[mi], bk[ni], ck[mi][ni]);
    __builtin_amdgcn_s_setprio(0);

    // ---- half 2: read bv (+sw), 16 MFMA cv (+4 side)
    bf16x8 bv[4], sw;
#pragma unroll
    for (int ni = 0; ni < 4; ++ni) bv[ni] = *(const bf16x8*)(lds + rb + 4096 + bro + ni * 512);
    if (side) sw = *(const bf16x8*)(lds + rb + swo);
    LGK0;
    __builtin_amdgcn_s_setprio(1);
#pragma unroll
    for (int mi = 0; mi < 4; ++mi)
#pragma unroll
      for (int ni = 0; ni < 4; ++ni)
        cv[mi][ni] = MFMA16(a[mi], bv[ni], cv[mi][ni]);
    if (side) {
#pragma unroll
      for (int mi = 0; mi < 4; ++mi) qa[mi] = MFMA16(a[mi], sw, qa[mi]);
    }
    __builtin_amdgcn_s_setprio(0);

    // ---- boundary: drain A(t+1) (and B(t+1..t+2)), keep B(t+3) in flight
    if (st1) {
      if (st3) {
        if (swv) { asm volatile("s_waitcnt vmcnt(3)" ::: "memory"); }
        else     { asm volatile("s_waitcnt vmcnt(2)" ::: "memory"); }
      } else {
        asm volatile("s_waitcnt vmcnt(0)" ::: "memory");
      }
      __builtin_amdgcn_s_barrier();
    }
  }

  // ---- epilogue: dots = per-head sum over 64 cols of ck*cv ----
  float part[4][4];
#pragma unroll
  for (int mi = 0; mi < 4; ++mi)
#pragma unroll
    for (int q = 0; q < 4; ++q) {
      float s = 0.f;
#pragma unroll
      for (int ni = 0; ni < 4; ++ni) s += ck[mi][ni][q] * cv[mi][ni][q];
      part[mi][q] = s;
    }
#pragma unroll
  for (int r = 0; r < 4; ++r) {
#pragma unroll
    for (int mi = 0; mi < 4; ++mi)
#pragma unroll
      for (int q = 0; q < 4; ++q)
        part[mi][q] += __shfl_xor(part[mi][q], 1 << r, 64);
  }
  int h = bx * 2 + wcN;
  if (fr == 0) {
#pragma unroll
    for (int mi = 0; mi < 4; ++mi)
#pragma unroll
      for (int q = 0; q < 4; ++q)
        dotsT[(size_t)h * 16384 + row0 + wrM * 64 + mi * 16 + fg * 4 + q] = part[mi][q];
  }
  if (side) {
    float* dst = (wcN == 0) ? qsumT : dotbT;
#pragma unroll
    for (int mi = 0; mi < 4; ++mi)
#pragma unroll
      for (int q = 0; q < 4; ++q)
        dst[(size_t)fr * 16384 + row0 + wrM * 64 + mi * 16 + fg * 4 + q] = qa[mi][q];
  }
}

// ---------------- cumsum + coef + state ----------------
__global__ void k_cumsum(const float* __restrict__ dotsT, const float* __restrict__ dotbT,
                         const float* __restrict__ qsumT, const float* __restrict__ scal,
                         const float* __restrict__ mask,
                         float* __restrict__ coef, float* __restrict__ state) {
  __shared__ float csum[256];
  int b = blockIdx.x >> 4, h = blockIdx.x & 15;
  int t = threadIdx.x;
  float bqs = scal[h], dbc = scal[16 + h];
  size_t m0 = (size_t)b * 4096;
  const float* dro = dotsT + (size_t)h * 16384 + m0;
  const float* dbo = dotbT + (size_t)h * 16384 + m0;
  const float* qso = qsumT + (size_t)h * 16384 + m0;
  const float* mko = mask + m0;
  float loc[16], run = 0.f;
  int s0 = t * 16;
#pragma unroll
  for (int i = 0; i < 16; ++i) {
    int ii = s0 + i;
    float mk = mko[ii];
    float d = (dro[ii] + dbo[ii] + dbc) * mk * mk;
    run += d;
    loc[i] = run;
  }
  csum[t] = run;
  __syncthreads();
  for (int off = 1; off < 256; off <<= 1) {
    float v = (t >= off) ? csum[t - off] : 0.f;
    __syncthreads();
    csum[t] += v;
    __syncthreads();
  }
  float prefix = csum[t] - run;
#pragma unroll
  for (int i = 0; i < 16; ++i) {
    int ii = s0 + i;
    float cum = prefix + loc[i];
    coef[(m0 + ii) * 16 + h] = cum * (qso[ii] + bqs);
  }
  float total = csum[255];
  float* sp = state + (size_t)(b * 16 + h) * 4096;
  for (int i = t; i < 4096; i += 256) sp[i] = total;
}

// ---------------- output GEMM: out = coef(16384x16) @ WosT(16x1024) + bo ----------------
__global__ __launch_bounds__(256) void k_outgemm(const float* __restrict__ coef,
                                                 const float* __restrict__ WosT,
                                                 const float* __restrict__ bo,
                                                 float* __restrict__ out) {
  int t = threadIdx.x;
  int j0 = t * 4;
  f32x4 w4[16];
#pragma unroll
  for (int hh = 0; hh < 16; ++hh) w4[hh] = *(const f32x4*)&WosT[hh * 1024 + j0];
  f32x4 bov = *(const f32x4*)&bo[j0];
  size_t m0 = (size_t)blockIdx.x * 32;
  for (int mi = 0; mi < 32; ++mi) {
    size_t m = m0 + mi;
    const float* cm = &coef[m * 16];
    f32x4 acc = bov;
#pragma unroll
    for (int hh = 0; hh < 16; ++hh) acc += w4[hh] * cm[hh];
    *(f32x4*)&out[m * 1024 + j0] = acc;
  }
}

extern "C" void kernel_launch(void* const* d_in, const int* in_sizes, int n_in,
                              void* d_out, int out_size, void* d_ws, size_t ws_size,
                              hipStream_t stream) {
  const float* X    = (const float*)d_in[0];
  const float* mask = (const float*)d_in[1];
  const float* Wq   = (const float*)d_in[2];
  const float* bq   = (const float*)d_in[3];
  const float* Wk   = (const float*)d_in[4];
  const float* bk   = (const float*)d_in[5];
  const float* Wv   = (const float*)d_in[6];
  const float* bv   = (const float*)d_in[7];
  const float* Wo   = (const float*)d_in[8];
  const float* bo   = (const float*)d_in[9];
  float* out   = (float*)d_out;
  float* state = out + (size_t)16384 * 1024;

  char* w = (char*)d_ws;
  unsigned short* Wkb = (unsigned short*)w; w += (size_t)1024 * 1024 * 2;
  unsigned short* Wvb = (unsigned short*)w; w += (size_t)1024 * 1024 * 2;
  unsigned short* SWb = (unsigned short*)w; w += (size_t)32 * 1024 * 2;
  float* WosT  = (float*)w; w += (size_t)16 * 1024 * 4;
  float* scal  = (float*)w; w += 256;
  float* dotsT = (float*)w; w += (size_t)16 * 16384 * 4;
  float* qsumT = (float*)w; w += (size_t)16 * 16384 * 4;
  float* dotbT = (float*)w; w += (size_t)16 * 16384 * 4;
  float* coef  = (float*)w; w += (size_t)16384 * 16 * 4;

  (void)hipFuncSetAttribute((const void*)k_dualgemm,
                            hipFuncAttributeMaxDynamicSharedMemorySize, 73728);

  hipLaunchKernelGGL(k_prep,     dim3(2241), dim3(256), 0, stream,
                     Wq, bq, Wk, bk, Wv, bv, Wo, Wkb, Wvb, SWb, WosT, scal);
  hipLaunchKernelGGL(k_dualgemm, dim3(512),  dim3(512), 73728, stream, X, Wkb, Wvb, SWb,
                     dotsT, qsumT, dotbT);
  hipLaunchKernelGGL(k_cumsum,   dim3(64),   dim3(256), 0, stream, dotsT, dotbT, qsumT, scal,
                     mask, coef, state);
  hipLaunchKernelGGL(k_outgemm,  dim3(512),  dim3(256), 0, stream, coef, WosT, bo, out);
}